// Round 7
// baseline (3513.200 us; speedup 1.0000x reference)
//
// Round 7: fuse x_proj + dt_proj into one kernel (k_xdt).
// R6 post-mortem: top-5 = one k_mfma @119.5us x8 (in_proj at the ~290 TF
// m97-structure plateau for N~2048 shapes). x_proj ran at 128 blocks x 128
// threads (half GPU idle); dt GEMM (K=32) re-staged A 8x and wrote 32 MB.
// Fix: k_xdt (256 blocks x 4 waves): phase 1 computes the 64x64 xdb tile
// (K=1024); cols 0..31 (xdt) go to LDS bf16 (pad 40), cols 32..63 (B/C) to
// global; phase 2 does dt = softplus(xdt @ Wdt^T + b) with 64 MFMAs/wave and
// stores fp16 into the xz x-half. Removes the dt dispatch + xdt buffer.
#include <hip/hip_runtime.h>
#include <hip/hip_bf16.h>
#include <hip/hip_fp16.h>
#include <math.h>

#define B_ 8
#define S_ 2048
#define H_ 512
#define DI_ 1024
#define DS_ 16
#define DC_ 4
#define DR_ 32
#define NL_ 8
#define NC_ 16
#define LC_ (S_ / NC_)  // 128
#define PF_ 4

typedef __hip_bfloat16 bf16;
typedef short bf16x8 __attribute__((ext_vector_type(8)));
typedef float f32x4 __attribute__((ext_vector_type(4)));

static __device__ __forceinline__ float wred_sum(float v) {
#pragma unroll
  for (int o = 32; o; o >>= 1) v += __shfl_down(v, o, 64);
  return v;
}
static __device__ __forceinline__ float bf2f(unsigned short u) {
  return __uint_as_float(((unsigned)u) << 16);
}
static __device__ __forceinline__ unsigned short f2bfbits(float v) {
  unsigned u = __float_as_uint(v);
  unsigned r = (u + 0x7fff + ((u >> 16) & 1)) >> 16;  // RNE
  return (unsigned short)r;
}
static __device__ __forceinline__ void st1(float* p, float v) { *p = v; }
static __device__ __forceinline__ void st1(bf16* p, float v) { *p = __float2bfloat16(v); }
static __device__ __forceinline__ void st1(__half* p, float v) { *p = __float2half(v); }

static __device__ __forceinline__ void gl_lds16(const unsigned short* g,
                                                unsigned short* l) {
  __builtin_amdgcn_global_load_lds(
      (const __attribute__((address_space(1))) void*)g,
      (__attribute__((address_space(3))) void*)l, 16, 0, 0);
}

// decay p[n] = exp(dt*A[n]).  FAST: A[n] == -(n0+n+1) => p[n] = q^(n0+n+1).
template <bool FAST>
static __device__ __forceinline__ void decay8(float dt, const float* A, int n0,
                                              float* p) {
  if constexpr (FAST) {
    float q = __expf(-dt);
    float q2 = q * q, q3 = q2 * q, q4 = q2 * q2;
    float l4 = q4 * q, l5 = q4 * q2, l6 = q4 * q3, q8 = q4 * q4;
    float s = n0 ? q8 : 1.f;
    p[0] = s * q;  p[1] = s * q2; p[2] = s * q3; p[3] = s * q4;
    p[4] = s * l4; p[5] = s * l5; p[6] = s * l6; p[7] = s * q8;
  } else {
#pragma unroll
    for (int n = 0; n < 8; n++) p[n] = __expf(dt * A[n]);
  }
}

// ---------------- MFMA GEMM: C[M,N] = X[M,K](bf16) @ W[N,K](bf16)^T ----------
template <int BM, int BN, int ACT, typename TC>
__global__ void __launch_bounds__((BM / 64) * (BN / 64) * 64) k_mfma(
    const unsigned short* __restrict__ X, int lda,
    const unsigned short* __restrict__ W, int ldb,
    const float* __restrict__ bias, TC* __restrict__ C, long ldc, int K) {
  constexpr int NW = (BM / 64) * (BN / 64);
  constexpr int WN = BN / 64;
  constexpr int SEGS = (BM + BN) / 16;
  __shared__ unsigned short As[BM * 32];
  __shared__ unsigned short Bs[BN * 32];
  int tid = threadIdx.x;
  int wave = tid >> 6, lane = tid & 63;
  int wm = wave / WN, wn = wave % WN;
  long row0 = (long)blockIdx.y * BM;
  long col0 = (long)blockIdx.x * BN;
  int srow = lane >> 2;
  int kchunk = (lane & 3) ^ (srow & 3);
  f32x4 acc[4][4] = {};
  for (int k0 = 0; k0 < K; k0 += 32) {
#pragma unroll
    for (int s = wave; s < SEGS; s += NW) {
      if (s < BM / 16) {
        const unsigned short* g =
            X + (row0 + s * 16 + srow) * (long)lda + k0 + kchunk * 8;
        gl_lds16(g, &As[s * 16 * 32]);
      } else {
        int s2 = s - BM / 16;
        const unsigned short* g =
            W + (col0 + s2 * 16 + srow) * (long)ldb + k0 + kchunk * 8;
        gl_lds16(g, &Bs[s2 * 16 * 32]);
      }
    }
    __syncthreads();
    int fr = lane & 15;
    int slot = (lane >> 4) ^ (lane & 3);
    bf16x8 af[4], bfr[4];
#pragma unroll
    for (int i = 0; i < 4; i++)
      af[i] = *(const bf16x8*)&As[(wm * 64 + i * 16 + fr) * 32 + slot * 8];
#pragma unroll
    for (int j = 0; j < 4; j++)
      bfr[j] = *(const bf16x8*)&Bs[(wn * 64 + j * 16 + fr) * 32 + slot * 8];
#pragma unroll
    for (int i = 0; i < 4; i++)
#pragma unroll
      for (int j = 0; j < 4; j++)
        acc[i][j] = __builtin_amdgcn_mfma_f32_16x16x32_bf16(af[i], bfr[j],
                                                            acc[i][j], 0, 0, 0);
    __syncthreads();
  }
#pragma unroll
  for (int i = 0; i < 4; i++) {
#pragma unroll
    for (int j = 0; j < 4; j++) {
      long rbase = row0 + wm * 64 + i * 16 + ((lane >> 4) << 2);
      long c = col0 + wn * 64 + j * 16 + (lane & 15);
#pragma unroll
      for (int reg = 0; reg < 4; reg++) {
        float v = acc[i][j][reg];
        long r = rbase + reg;
        if constexpr (ACT == 1) {
          v += bias[c];
          v = fmaxf(v, 0.f) + log1pf(__expf(-fabsf(v)));  // softplus
        }
        st1(&C[r * ldc + c], v);
      }
    }
  }
}

// ---------------- fused x_proj + dt_proj ----------------
// Block = 64 rows. Phase 1: xdb64 = xc_tile @ Wx^T (K=1024). Cols 0..31 (xdt)
// -> LDS bf16 [64][40]; cols 32..63 (B/C) -> xdb global (fp32). Phase 2:
// dt = softplus(xdt @ Wdt^T + bdt) -> fp16 store into xz x-half (stride 2048).
__global__ void __launch_bounds__(256) k_xdt(
    const unsigned short* __restrict__ Xc,   // xc bf16, lda=1024
    const unsigned short* __restrict__ Wx,   // 64x1024 bf16
    const unsigned short* __restrict__ Wdt,  // 1024x32 bf16
    const float* __restrict__ bdt,           // 1024 fp32
    float* __restrict__ xdb,                 // 16384x64 fp32 (cols 32:64 written)
    __half* __restrict__ dt) {               // stride 2048 (x-half of xz)
  __shared__ unsigned short As[64 * 32];  // 4 KB
  __shared__ unsigned short Bs[64 * 32];  // 4 KB
  __shared__ unsigned short Xt[64 * 40];  // 5 KB, pad 40 vs 32 (bank spread)
  int tid = threadIdx.x;
  int wave = tid >> 6, lane = tid & 63;
  int wm = wave >> 1, wn = wave & 1;
  long row0 = (long)blockIdx.x * 64;
  int srow = lane >> 2;
  int kchunk = (lane & 3) ^ (srow & 3);
  int fr = lane & 15;
  int q = lane >> 4;
  f32x4 acc[2][2] = {};
  for (int k0 = 0; k0 < DI_; k0 += 32) {
#pragma unroll
    for (int s = wave; s < 8; s += 4) {
      if (s < 4)
        gl_lds16(Xc + (row0 + s * 16 + srow) * (long)DI_ + k0 + kchunk * 8,
                 &As[s * 16 * 32]);
      else
        gl_lds16(Wx + ((s - 4) * 16 + srow) * (long)DI_ + k0 + kchunk * 8,
                 &Bs[(s - 4) * 16 * 32]);
    }
    __syncthreads();
    int slot = q ^ (lane & 3);
    bf16x8 af[2], bfr[2];
#pragma unroll
    for (int i = 0; i < 2; i++)
      af[i] = *(const bf16x8*)&As[(wm * 32 + i * 16 + fr) * 32 + slot * 8];
#pragma unroll
    for (int j = 0; j < 2; j++)
      bfr[j] = *(const bf16x8*)&Bs[(wn * 32 + j * 16 + fr) * 32 + slot * 8];
#pragma unroll
    for (int i = 0; i < 2; i++)
#pragma unroll
      for (int j = 0; j < 2; j++)
        acc[i][j] = __builtin_amdgcn_mfma_f32_16x16x32_bf16(af[i], bfr[j],
                                                            acc[i][j], 0, 0, 0);
    __syncthreads();
  }
  // epilogue phase 1: C/D layout col=lane&15, row=q*4+reg
#pragma unroll
  for (int i = 0; i < 2; i++) {
#pragma unroll
    for (int j = 0; j < 2; j++) {
      int c = wn * 32 + j * 16 + fr;
      int lr0 = wm * 32 + i * 16 + (q << 2);
#pragma unroll
      for (int reg = 0; reg < 4; reg++) {
        float v = acc[i][j][reg];
        int lr = lr0 + reg;
        if (c < 32)
          Xt[lr * 40 + c] = f2bfbits(v);  // xdt tile (bf16, same as old path)
        else
          xdb[(row0 + lr) * 64 + c] = v;  // B/C for the scan
      }
    }
  }
  __syncthreads();
  // phase 2: each wave computes dt cols [wave*256, wave*256+256)
  bf16x8 xa[4];
#pragma unroll
  for (int i = 0; i < 4; i++)
    xa[i] = *(const bf16x8*)&Xt[(i * 16 + fr) * 40 + q * 8];
#pragma unroll
  for (int nt = 0; nt < 16; nt++) {
    int c = wave * 256 + nt * 16 + fr;
    bf16x8 wb = *(const bf16x8*)&Wdt[(long)c * 32 + q * 8];
    float bv = bdt[c];
    f32x4 dacc[4] = {};
#pragma unroll
    for (int i = 0; i < 4; i++)
      dacc[i] = __builtin_amdgcn_mfma_f32_16x16x32_bf16(xa[i], wb, dacc[i], 0, 0, 0);
#pragma unroll
    for (int i = 0; i < 4; i++) {
#pragma unroll
      for (int reg = 0; reg < 4; reg++) {
        float v = dacc[i][reg] + bv;
        v = fmaxf(v, 0.f) + log1pf(__expf(-fabsf(v)));  // softplus
        long r = row0 + i * 16 + (q << 2) + reg;
        st1(&dt[r * 2048 + c], v);
      }
    }
  }
}

// ---------------- weight fp32 -> bf16 conversion ----------------
__global__ void k_convert4(const float* __restrict__ s0, int n0,
                           const float* __restrict__ s1, int n1,
                           const float* __restrict__ s2, int n2,
                           const float* __restrict__ s3, int n3,
                           bf16* __restrict__ d0, bf16* __restrict__ d1,
                           bf16* __restrict__ d2, bf16* __restrict__ d3) {
  int i = blockIdx.x * 256 + threadIdx.x;
  int t0 = n0 >> 2, t1 = t0 + (n1 >> 2), t2 = t1 + (n2 >> 2), t3 = t2 + (n3 >> 2);
  const float* s;
  bf16* d;
  int loc;
  if (i < t0) { s = s0; d = d0; loc = i; }
  else if (i < t1) { s = s1; d = d1; loc = i - t0; }
  else if (i < t2) { s = s2; d = d2; loc = i - t1; }
  else if (i < t3) { s = s3; d = d3; loc = i - t2; }
  else return;
  float4 v = ((const float4*)s)[loc];
  bf16* o = d + (long)loc * 4;
  st1(o + 0, v.x); st1(o + 1, v.y); st1(o + 2, v.z); st1(o + 3, v.w);
}

// ---------------- K1: embedding + LN + gate ----------------
__global__ void k_embed(const int* __restrict__ ids, const float* __restrict__ gate,
                        const float* __restrict__ wemb, const float* __restrict__ pos2,
                        const float* __restrict__ pe, const float* __restrict__ g,
                        const float* __restrict__ bta, bf16* __restrict__ seq) {
  int row = blockIdx.x;
  int s = row % S_;
  int t = threadIdx.x;
  int id = ids[row];
  float v[2];
#pragma unroll
  for (int i = 0; i < 2; i++) {
    int h = t + i * 256;
    v[i] = pos2[s * H_ + h] * wemb[(long)id * H_ + h] + pe[s * H_ + h];
  }
  float lsum = v[0] + v[1];
  float lsq = v[0] * v[0] + v[1] * v[1];
  __shared__ float smA[4], smB[4];
  int lane = t & 63, w = t >> 6;
  lsum = wred_sum(lsum);
  lsq = wred_sum(lsq);
  if (!lane) { smA[w] = lsum; smB[w] = lsq; }
  __syncthreads();
  float tot = smA[0] + smA[1] + smA[2] + smA[3];
  float totq = smB[0] + smB[1] + smB[2] + smB[3];
  float mu = tot * (1.f / H_);
  float var = totq * (1.f / H_) - mu * mu;
  float inv = rsqrtf(fmaxf(var, 0.f) + 1e-12f);
  float gt = gate[row];
#pragma unroll
  for (int i = 0; i < 2; i++) {
    int h = t + i * 256;
    st1(&seq[(long)row * H_ + h], gt * (g[h] * (v[i] - mu) * inv + bta[h]));
  }
}

// ---------------- conv (depthwise causal, DC=4) + silu ----------------
__global__ void k_conv(const bf16* __restrict__ xz, const float* __restrict__ cw,
                       const float* __restrict__ cb, bf16* __restrict__ xc) {
  long idx = (long)blockIdx.x * 256 + threadIdx.x;
  int d = (int)(idx & 1023);
  long bt = idx >> 10;
  int t = (int)(bt & 2047);
  const unsigned short* xbase = (const unsigned short*)xz + (bt - t) * 2048 + d;
  float acc = cb[d];
#pragma unroll
  for (int k = 0; k < 4; k++) {
    int ts = t + k - 3;
    if (ts >= 0) acc += cw[d * 4 + k] * bf2f(xbase[(long)ts * 2048]);
  }
  float s = acc / (1.f + __expf(-acc));
  st1(&xc[idx], s);
}

// ---------------- serial scan (fallback when ws too small) ----------------
__global__ void __launch_bounds__(64) k_scan(
    bf16* __restrict__ xzb, const bf16* __restrict__ xc,
    const float* __restrict__ xdb, const float* __restrict__ Alog,
    const float* __restrict__ Dp) {
  int idx = blockIdx.x * 64 + threadIdx.x;
  int half = idx & 1;
  int p = idx >> 1;
  int d = p & 1023;
  int b = p >> 10;
  int n0 = half * 8;
  float A[8];
#pragma unroll
  for (int n = 0; n < 8; n++) A[n] = -__expf(Alog[d * 16 + n0 + n]);
  float Dd = Dp[d];
  float h[8] = {0, 0, 0, 0, 0, 0, 0, 0};
  const __half* dtb = (const __half*)xzb + (long)b * S_ * 2048 + d;
  const unsigned short* xb = (const unsigned short*)xc + (long)b * S_ * DI_ + d;
  const unsigned short* zb = (const unsigned short*)xzb + (long)b * S_ * 2048 + DI_ + d;
  const float* bcb = xdb + (long)b * S_ * 64 + DR_ + n0;
  bf16* yb = xzb + (long)b * S_ * 2048 + d;
  float dt_c = __half2float(dtb[0]);
  float x_c = bf2f(xb[0]);
  float z_c = bf2f(zb[0]);
  float Bc[8], Cc[8];
#pragma unroll
  for (int n = 0; n < 8; n++) { Bc[n] = bcb[n]; Cc[n] = bcb[16 + n]; }
  for (int t = 0; t < S_; t++) {
    float dt_n = 0.f, x_n = 0.f, z_n = 0.f, Bn[8], Cn[8];
#pragma unroll
    for (int n = 0; n < 8; n++) { Bn[n] = 0.f; Cn[n] = 0.f; }
    if (t + 1 < S_) {
      long o = (long)(t + 1);
      dt_n = __half2float(dtb[o * 2048]);
      x_n = bf2f(xb[o * DI_]);
      z_n = bf2f(zb[o * 2048]);
      const float* bc = bcb + o * 64;
#pragma unroll
      for (int n = 0; n < 8; n++) { Bn[n] = bc[n]; Cn[n] = bc[16 + n]; }
    }
    float dx = dt_c * x_c;
    float yacc = 0.f;
#pragma unroll
    for (int n = 0; n < 8; n++) {
      float hn = __expf(dt_c * A[n]) * h[n] + dx * Bc[n];
      h[n] = hn;
      yacc += hn * Cc[n];
    }
    yacc += __shfl_xor(yacc, 1, 64);
    if (!half) {
      float sz = z_c / (1.f + __expf(-z_c));
      st1(&yb[(long)t * 2048], (yacc + Dd * x_c) * sz);
    }
    dt_c = dt_n; x_c = x_n; z_c = z_n;
#pragma unroll
    for (int n = 0; n < 8; n++) { Bc[n] = Bn[n]; Cc[n] = Cn[n]; }
  }
}

// ---------------- chunked scan phase A body ----------------
template <bool FAST>
static __device__ __forceinline__ void scanA_body(
    const __half* dtb, const unsigned short* xb, const float* bcb,
    const float* A, int n0, int t0, float* h, float& sd) {
  float dtv[PF_], xv[PF_];
  f32x4 Bv0[PF_], Bv1[PF_];
#pragma unroll
  for (int i = 0; i < PF_; i++) {
    long o = t0 + i;
    dtv[i] = __half2float(dtb[o * 2048]);
    xv[i] = bf2f(xb[o * DI_]);
    Bv0[i] = *(const f32x4*)(bcb + o * 64);
    Bv1[i] = *(const f32x4*)(bcb + o * 64 + 4);
  }
  for (int t = 0; t < LC_; t += PF_) {
#pragma unroll
    for (int u = 0; u < PF_; u++) {
      float dt_c = dtv[u], x_c = xv[u];
      f32x4 b0 = Bv0[u], b1 = Bv1[u];
      long o = t0 + t + u + PF_;
      if (o > S_ - 1) o = S_ - 1;  // harmless re-read (read-only in phase A)
      dtv[u] = __half2float(dtb[o * 2048]);
      xv[u] = bf2f(xb[o * DI_]);
      Bv0[u] = *(const f32x4*)(bcb + o * 64);
      Bv1[u] = *(const f32x4*)(bcb + o * 64 + 4);
      sd += dt_c;
      float dx = dt_c * x_c;
      float p[8];
      decay8<FAST>(dt_c, A, n0, p);
#pragma unroll
      for (int n = 0; n < 4; n++) h[n] = p[n] * h[n] + dx * b0[n];
#pragma unroll
      for (int n = 0; n < 4; n++) h[4 + n] = p[4 + n] * h[4 + n] + dx * b1[n];
    }
  }
}

// grid (NC-1)*256 x 64: chunks 0..NC-2 (last chunk h_final unused).
__global__ void __launch_bounds__(64) k_scanA(
    const bf16* __restrict__ xzb, const bf16* __restrict__ xc,
    const float* __restrict__ xdb, const float* __restrict__ Alog,
    __half* __restrict__ hf, __half* __restrict__ sdt) {
  int idx = blockIdx.x * 64 + threadIdx.x;
  int pf = idx & 16383;
  int c = idx >> 14;
  int half = pf & 1;
  int p = pf >> 1;
  int d = p & 1023;
  int b = p >> 10;
  int n0 = half * 8;
  float A[8];
  bool fast = true;
#pragma unroll
  for (int n = 0; n < 8; n++) {
    A[n] = -__expf(Alog[d * 16 + n0 + n]);
    fast = fast && (fabsf(A[n] + (float)(n0 + n + 1)) < 1e-3f);
  }
  const __half* dtb = (const __half*)xzb + (long)b * S_ * 2048 + d;
  const unsigned short* xb = (const unsigned short*)xc + (long)b * S_ * DI_ + d;
  const float* bcb = xdb + (long)b * S_ * 64 + DR_ + n0;
  int t0 = c * LC_;
  float h[8] = {0, 0, 0, 0, 0, 0, 0, 0};
  float sd = 0.f;
  if (fast) scanA_body<true>(dtb, xb, bcb, A, n0, t0, h, sd);
  else scanA_body<false>(dtb, xb, bcb, A, n0, t0, h, sd);
  __half* ho = hf + (long)idx * 8;
#pragma unroll
  for (int n = 0; n < 8; n++) st1(&ho[n], h[n]);
  if (!half) st1(&sdt[c * 8192 + p], sd);
}

// ---------------- chunked scan phase C body ----------------
template <bool FAST>
static __device__ __forceinline__ void scanC_body(
    const __half* dtb, const unsigned short* xb, const unsigned short* zb,
    const float* bcb, bf16* yb, const float* A, int n0, int half, int t0,
    float Dd, float* h) {
  int tend = t0 + LC_ - 1;  // prefetch clamp: stay in own chunk (y overwrites dt)
  float dtv[PF_], xv[PF_], zv[PF_];
  f32x4 Bv0[PF_], Bv1[PF_], Cv0[PF_], Cv1[PF_];
#pragma unroll
  for (int i = 0; i < PF_; i++) {
    long o = t0 + i;
    dtv[i] = __half2float(dtb[o * 2048]);
    xv[i] = bf2f(xb[o * DI_]);
    zv[i] = bf2f(zb[o * 2048]);
    Bv0[i] = *(const f32x4*)(bcb + o * 64);
    Bv1[i] = *(const f32x4*)(bcb + o * 64 + 4);
    Cv0[i] = *(const f32x4*)(bcb + o * 64 + 16);
    Cv1[i] = *(const f32x4*)(bcb + o * 64 + 20);
  }
  for (int t = 0; t < LC_; t += PF_) {
#pragma unroll
    for (int u = 0; u < PF_; u++) {
      float dt_c = dtv[u], x_c = xv[u], z_c = zv[u];
      f32x4 b0 = Bv0[u], b1 = Bv1[u], c0 = Cv0[u], c1 = Cv1[u];
      long o = t0 + t + u + PF_;
      if (o > tend) o = tend;
      dtv[u] = __half2float(dtb[o * 2048]);
      xv[u] = bf2f(xb[o * DI_]);
      zv[u] = bf2f(zb[o * 2048]);
      Bv0[u] = *(const f32x4*)(bcb + o * 64);
      Bv1[u] = *(const f32x4*)(bcb + o * 64 + 4);
      Cv0[u] = *(const f32x4*)(bcb + o * 64 + 16);
      Cv1[u] = *(const f32x4*)(bcb + o * 64 + 20);
      float dx = dt_c * x_c;
      float p[8];
      decay8<FAST>(dt_c, A, n0, p);
      float yacc = 0.f;
#pragma unroll
      for (int n = 0; n < 4; n++) {
        float hn = p[n] * h[n] + dx * b0[n];
        h[n] = hn;
        yacc += hn * c0[n];
      }
#pragma unroll
      for (int n = 0; n < 4; n++) {
        float hn = p[4 + n] * h[4 + n] + dx * b1[n];
        h[4 + n] = hn;
        yacc += hn * c1[n];
      }
      yacc += __shfl_xor(yacc, 1, 64);
      if (!half) {
        float sz = z_c / (1.f + __expf(-z_c));
        st1(&yb[(long)(t0 + t + u) * 2048], (yacc + Dd * x_c) * sz);
      }
    }
  }
}

__global__ void __launch_bounds__(64) k_scanC(
    bf16* __restrict__ xzb, const bf16* __restrict__ xc,
    const float* __restrict__ xdb, const float* __restrict__ Alog,
    const float* __restrict__ Dp, const __half* __restrict__ hf,
    const __half* __restrict__ sdt) {
  int idx = blockIdx.x * 64 + threadIdx.x;
  int pf = idx & 16383;
  int c = idx >> 14;  // wave-uniform
  int half = pf & 1;
  int p = pf >> 1;
  int d = p & 1023;
  int b = p >> 10;
  int n0 = half * 8;
  float A[8];
  bool fast = true;
#pragma unroll
  for (int n = 0; n < 8; n++) {
    A[n] = -__expf(Alog[d * 16 + n0 + n]);
    fast = fast && (fabsf(A[n] + (float)(n0 + n + 1)) < 1e-3f);
  }
  float Dd = Dp[d];
  float h[8] = {0, 0, 0, 0, 0, 0, 0, 0};
  if (fast) {
    for (int j = 0; j < c; j++) {
      float sd = __half2float(sdt[j * 8192 + p]);
      const __half* hj = hf + ((long)j * 16384 + pf) * 8;
      float pw[8];
      decay8<true>(sd, A, n0, pw);
#pragma unroll
      for (int n = 0; n < 8; n++) h[n] = pw[n] * h[n] + __half2float(hj[n]);
    }
  } else {
    for (int j = 0; j < c; j++) {
      float sd = __half2float(sdt[j * 8192 + p]);
      const __half* hj = hf + ((long)j * 16384 + pf) * 8;
      float pw[8];
      decay8<false>(sd, A, n0, pw);
#pragma unroll
      for (int n = 0; n < 8; n++) h[n] = pw[n] * h[n] + __half2float(hj[n]);
    }
  }
  const __half* dtb = (const __half*)xzb + (long)b * S_ * 2048 + d;
  const unsigned short* xb = (const unsigned short*)xc + (long)b * S_ * DI_ + d;
  const unsigned short* zb = (const unsigned short*)xzb + (long)b * S_ * 2048 + DI_ + d;
  const float* bcb = xdb + (long)b * S_ * 64 + DR_ + n0;
  bf16* yb = xzb + (long)b * S_ * 2048 + d;
  int t0 = c * LC_;
  if (fast) scanC_body<true>(dtb, xb, zb, bcb, yb, A, n0, half, t0, Dd, h);
  else scanC_body<false>(dtb, xb, zb, bcb, yb, A, n0, half, t0, Dd, h);
}

// ---------------- residual + LN + gate (in-place on seq) ----------------
__global__ void k_resid_ln(const bf16* __restrict__ hb, const float* __restrict__ gate,
                           const float* __restrict__ g, const float* __restrict__ bta,
                           bf16* __restrict__ seq) {
  int row = blockIdx.x;
  int t = threadIdx.x;
  float v[2];
#pragma unroll
  for (int i = 0; i < 2; i++) {
    int h = t + i * 256;
    v[i] = bf2f(((const unsigned short*)hb)[(long)row * H_ + h]) +
           bf2f(((const unsigned short*)seq)[(long)row * H_ + h]);
  }
  float lsum = v[0] + v[1];
  float lsq = v[0] * v[0] + v[1] * v[1];
  __shared__ float smA[4], smB[4];
  int lane = t & 63, w = t >> 6;
  lsum = wred_sum(lsum);
  lsq = wred_sum(lsq);
  if (!lane) { smA[w] = lsum; smB[w] = lsq; }
  __syncthreads();
  float tot = smA[0] + smA[1] + smA[2] + smA[3];
  float totq = smB[0] + smB[1] + smB[2] + smB[3];
  float mu = tot * (1.f / H_);
  float var = totq * (1.f / H_) - mu * mu;
  float inv = rsqrtf(fmaxf(var, 0.f) + 1e-12f);
  float gt = gate[row];
#pragma unroll
  for (int i = 0; i < 2; i++) {
    int h = t + i * 256;
    st1(&seq[(long)row * H_ + h], gt * (g[h] * (v[i] - mu) * inv + bta[h]));
  }
}

// ---------------- max pool (two stage) ----------------
__global__ void k_pool1(const bf16* __restrict__ seq, const float* __restrict__ gate,
                        float* __restrict__ part) {
  int blk = blockIdx.x;
  int b = blk >> 4, c = blk & 15;
  int h = threadIdx.x;
  float m = -3.4e38f;
  for (int i = 0; i < 128; i++) {
    long r = (long)b * S_ + c * 128 + i;
    m = fmaxf(m, bf2f(((const unsigned short*)seq)[r * H_ + h]) * gate[r]);
  }
  part[((long)b * 16 + c) * H_ + h] = m;
}
__global__ void k_pool2(const float* __restrict__ part, float* __restrict__ pooled) {
  int idx = blockIdx.x * 256 + threadIdx.x;
  int b = idx >> 9, h = idx & 511;
  float m = -3.4e38f;
#pragma unroll
  for (int c = 0; c < 16; c++) m = fmaxf(m, part[((long)b * 16 + c) * H_ + h]);
  pooled[idx] = m;
}

// ---------------- dense2 + gelu_new ----------------
__global__ void k_feat(const float* __restrict__ pooled, const float* __restrict__ W2,
                       const float* __restrict__ b2, float* __restrict__ feat) {
  int b = blockIdx.x;
  int j = threadIdx.x;
  __shared__ float ps[512];
  ps[j] = pooled[b * 512 + j];
  __syncthreads();
  float acc = b2[j];
  const float* wr = W2 + (long)j * 512;
  for (int k = 0; k < 512; k++) acc += ps[k] * wr[k];
  float x = acc;
  float u = 0.7978845608028654f * (x + 0.044715f * x * x * x);
  feat[b * 512 + j] = 0.5f * x * (1.f + tanhf(u));
}

// ---------------- GroupNorm + FiLM(style) + head ----------------
__global__ void k_head(const float* __restrict__ feat, const float* __restrict__ age_sex,
                       const float* __restrict__ mw, const float* __restrict__ mb,
                       const float* __restrict__ gng, const float* __restrict__ gnb,
                       const float* __restrict__ hw, const float* __restrict__ hb,
                       float* __restrict__ out) {
  int b = blockIdx.x;
  int j = threadIdx.x;
  float f = feat[b * 512 + j];
  __shared__ float sA[8], sB[8];
  int lane = j & 63, w = j >> 6;
  float s1 = wred_sum(f);
  float s2 = wred_sum(f * f);
  if (!lane) { sA[w] = s1; sB[w] = s2; }
  __syncthreads();
  int g = j >> 7;
  float tot = sA[2 * g] + sA[2 * g + 1];
  float totq = sB[2 * g] + sB[2 * g + 1];
  float mu = tot * (1.f / 128.f);
  float var = totq * (1.f / 128.f) - mu * mu;
  float gn = (f - mu) * rsqrtf(fmaxf(var, 0.f) + 1e-5f) * gng[j] + gnb[j];
  float a0 = age_sex[b * 2], a1 = age_sex[b * 2 + 1];
  float sa = a0 * mw[j * 2] + a1 * mw[j * 2 + 1] + mb[j];
  sa = sa > 0.f ? sa : (__expf(sa) - 1.f);
  int j2 = 512 + j;
  float sb = a0 * mw[j2 * 2] + a1 * mw[j2 * 2 + 1] + mb[j2];
  sb = sb > 0.f ? sb : (__expf(sb) - 1.f);
  float feature = (1.f + sa) * gn + sb;
  out[16 + 16384 + b * 512 + j] = feature;
  float l0 = feature * hw[j];
  float l1 = feature * hw[512 + j];
  __syncthreads();
  l0 = wred_sum(l0);
  l1 = wred_sum(l1);
  if (!lane) { sA[w] = l0; sB[w] = l1; }
  __syncthreads();
  if (j == 0) {
    float t0 = 0.f, t1 = 0.f;
#pragma unroll
    for (int i = 0; i < 8; i++) { t0 += sA[i]; t1 += sB[i]; }
    out[b * 2 + 0] = t0 + hb[0];
    out[b * 2 + 1] = t1 + hb[1];
  }
}

__global__ void k_copy(const float* __restrict__ src, float* __restrict__ dst, int n) {
  int i = blockIdx.x * 256 + threadIdx.x;
  if (i < n) dst[i] = src[i];
}

// ---------------- launch ----------------
extern "C" void kernel_launch(void* const* d_in, const int* in_sizes, int n_in,
                              void* d_out, int out_size, void* d_ws, size_t ws_size,
                              hipStream_t stream) {
  const int* ids = (const int*)d_in[0];
  const float* gate = (const float*)d_in[1];
  const float* age_sex = (const float*)d_in[2];
  const float* word_emb = (const float*)d_in[3];
  const float* pos_emb2 = (const float*)d_in[4];
  const float* pe = (const float*)d_in[5];
  const float* emb_ln_g = (const float*)d_in[6];
  const float* emb_ln_b = (const float*)d_in[7];
  const float* in_proj_w = (const float*)d_in[8];
  const float* conv_w = (const float*)d_in[9];
  const float* conv_b = (const float*)d_in[10];
  const float* x_proj_w = (const float*)d_in[11];
  const float* dt_proj_w = (const float*)d_in[12];
  const float* dt_proj_b = (const float*)d_in[13];
  const float* A_log = (const float*)d_in[14];
  const float* D_param = (const float*)d_in[15];
  const float* out_proj_w = (const float*)d_in[16];
  const float* blk_ln_g = (const float*)d_in[17];
  const float* blk_ln_b = (const float*)d_in[18];
  const float* dense2_w = (const float*)d_in[19];
  const float* dense2_b = (const float*)d_in[20];
  const float* male_fc_w = (const float*)d_in[21];
  const float* male_fc_b = (const float*)d_in[22];
  const float* gn_g = (const float*)d_in[23];
  const float* gn_b = (const float*)d_in[24];
  const float* head_w = (const float*)d_in[25];
  const float* head_b = (const float*)d_in[26];
  float* out = (float*)d_out;

  // ws layout (bytes): footprint 130,777,088 (same as R5/R6 passing layout)
  char* w = (char*)d_ws;
  bf16* seq = (bf16*)(w);
  bf16* xz = (bf16*)(w + 16777216);
  bf16* xc = (bf16*)(w + 83886080);
  float* xdb = (float*)(w + 117440512);
  bf16* wi_b = (bf16*)(w + 122683392);
  bf16* wx_b = (bf16*)(w + 124780544);
  bf16* wdt_b = (bf16*)(w + 124911616);
  bf16* wo_b = (bf16*)(w + 124977152);
  float* part = (float*)(w + 126025728);
  float* pooled = (float*)(w + 126287872);
  float* featp = (float*)(w + 126304256);
  __half* hf = (__half*)(w + 126320640);   // (NC-1)*16384*8*2 B (slot 4 MiB)
  __half* sdt = (__half*)(w + 130514944);  // (NC-1)*8192*2 B (slot 256 KiB)
  const bool chunked = ws_size >= (size_t)130777088;

  k_embed<<<B_ * S_, 256, 0, stream>>>(ids, gate, word_emb, pos_emb2, pe, emb_ln_g,
                                       emb_ln_b, seq);

  const int nWi = 2 * DI_ * H_;
  const int nWx = 64 * DI_;
  const int nWdt = DI_ * DR_;
  const int nWo = H_ * DI_;
  const int cvt_blocks = (nWi + nWx + nWdt + nWo) / 4 / 256;

  for (int l = 0; l < NL_; l++) {
    const float* Wi = in_proj_w + (long)l * nWi;
    const float* cw = conv_w + (long)l * DI_ * DC_;
    const float* cb = conv_b + (long)l * DI_;
    const float* Wx = x_proj_w + (long)l * nWx;
    const float* Wdt = dt_proj_w + (long)l * nWdt;
    const float* bdt = dt_proj_b + (long)l * DI_;
    const float* Al = A_log + (long)l * DI_ * DS_;
    const float* Dl = D_param + (long)l * DI_;
    const float* Wo = out_proj_w + (long)l * nWo;
    const float* bg = blk_ln_g + (long)l * H_;
    const float* bb = blk_ln_b + (long)l * H_;

    k_convert4<<<cvt_blocks, 256, 0, stream>>>(Wi, nWi, Wx, nWx, Wdt, nWdt, Wo, nWo,
                                               wi_b, wx_b, wdt_b, wo_b);

    // xz = seq @ Wi^T
    k_mfma<128, 128, 0, bf16><<<dim3(16, 128), 256, 0, stream>>>(
        (const unsigned short*)seq, H_, (const unsigned short*)wi_b, H_, nullptr,
        xz, 2048, H_);
    // conv + silu -> xc
    k_conv<<<(B_ * S_ * DI_) / 256, 256, 0, stream>>>(xz, cw, cb, xc);
    // fused x_proj + dt_proj: xdb cols 32:64 (fp32) + dt (fp16 into xz x-half)
    k_xdt<<<256, 256, 0, stream>>>(
        (const unsigned short*)xc, (const unsigned short*)wx_b,
        (const unsigned short*)wdt_b, bdt, xdb, (__half*)xz);
    if (chunked) {
      k_scanA<<<(NC_ - 1) * 256, 64, 0, stream>>>(xz, xc, xdb, Al, hf, sdt);
      k_scanC<<<NC_ * 256, 64, 0, stream>>>(xz, xc, xdb, Al, Dl, hf, sdt);
    } else {
      k_scan<<<256, 64, 0, stream>>>(xz, xc, xdb, Al, Dl);
    }
    // h = y @ Wo^T -> hbuf (= xc region)
    k_mfma<128, 128, 0, bf16><<<dim3(4, 128), 256, 0, stream>>>(
        (const unsigned short*)xz, 2048, (const unsigned short*)wo_b, DI_, nullptr,
        xc, H_, DI_);
    k_resid_ln<<<B_ * S_, 256, 0, stream>>>(xc, gate, bg, bb, seq);
  }

  k_pool1<<<B_ * 16, 512, 0, stream>>>(seq, gate, part);
  k_pool2<<<16, 256, 0, stream>>>(part, pooled);
  k_feat<<<B_, 512, 0, stream>>>(pooled, dense2_w, dense2_b, featp);
  k_head<<<B_, 512, 0, stream>>>(featp, age_sex, male_fc_w, male_fc_b, gn_g, gn_b,
                                 head_w, head_b, out);
  k_copy<<<(B_ * S_ + 255) / 256, 256, 0, stream>>>(gate, out + 16, B_ * S_);
}

// Round 8
// 3494.683 us; speedup vs baseline: 1.0053x; 1.0053x over previous
//
// Round 8: 3-phase chunked scan (A/B/C), clamp-free inner loops, NC=32.
// R7 post-mortem: scanC stuck at ~107us. Causes: (1) per-step prefetch clamp
// on all 7 load streams -> cndmask + 64-bit addr recompute per stream per
// step; (2) every scanC thread redundantly folds <=NC-1 chunk summaries;
// (3) 64-thread WGs cap resident waves. Fix: NC=32 (8192 waves = 32/CU),
// new k_scanB prefix-folds summaries in place (scanC combine = one 16B load),
// clamp only the dt stream (y overwrites dt; x/z/B/C overreads land in
// adjacent ws regions, verified in-bounds, values unused), 256-thread WGs.
// B/C repacked to 32-float rows; ws total 131,809,280 B (serial fallback kept).
#include <hip/hip_runtime.h>
#include <hip/hip_bf16.h>
#include <hip/hip_fp16.h>
#include <math.h>

#define B_ 8
#define S_ 2048
#define H_ 512
#define DI_ 1024
#define DS_ 16
#define DC_ 4
#define DR_ 32
#define NL_ 8
#define NC_ 32
#define LC_ (S_ / NC_)  // 64
#define PF_ 4

typedef __hip_bfloat16 bf16;
typedef short bf16x8 __attribute__((ext_vector_type(8)));
typedef float f32x4 __attribute__((ext_vector_type(4)));
typedef unsigned short u16x8 __attribute__((ext_vector_type(8)));

static __device__ __forceinline__ float wred_sum(float v) {
#pragma unroll
  for (int o = 32; o; o >>= 1) v += __shfl_down(v, o, 64);
  return v;
}
static __device__ __forceinline__ float bf2f(unsigned short u) {
  return __uint_as_float(((unsigned)u) << 16);
}
static __device__ __forceinline__ unsigned short f2bfbits(float v) {
  unsigned u = __float_as_uint(v);
  unsigned r = (u + 0x7fff + ((u >> 16) & 1)) >> 16;  // RNE
  return (unsigned short)r;
}
static __device__ __forceinline__ unsigned short h2bits(float v) {
  __half h = __float2half(v);
  return *reinterpret_cast<unsigned short*>(&h);
}
static __device__ __forceinline__ float bits2h(unsigned short u) {
  __half h;
  *reinterpret_cast<unsigned short*>(&h) = u;
  return __half2float(h);
}
static __device__ __forceinline__ void st1(float* p, float v) { *p = v; }
static __device__ __forceinline__ void st1(bf16* p, float v) { *p = __float2bfloat16(v); }
static __device__ __forceinline__ void st1(__half* p, float v) { *p = __float2half(v); }

static __device__ __forceinline__ void gl_lds16(const unsigned short* g,
                                                unsigned short* l) {
  __builtin_amdgcn_global_load_lds(
      (const __attribute__((address_space(1))) void*)g,
      (__attribute__((address_space(3))) void*)l, 16, 0, 0);
}

// decay p[n] = exp(dt*A[n]).  FAST: A[n] == -(n0+n+1) => p[n] = q^(n0+n+1).
template <bool FAST>
static __device__ __forceinline__ void decay8(float dt, const float* A, int n0,
                                              float* p) {
  if constexpr (FAST) {
    float q = __expf(-dt);
    float q2 = q * q, q3 = q2 * q, q4 = q2 * q2;
    float l4 = q4 * q, l5 = q4 * q2, l6 = q4 * q3, q8 = q4 * q4;
    float s = n0 ? q8 : 1.f;
    p[0] = s * q;  p[1] = s * q2; p[2] = s * q3; p[3] = s * q4;
    p[4] = s * l4; p[5] = s * l5; p[6] = s * l6; p[7] = s * q8;
  } else {
#pragma unroll
    for (int n = 0; n < 8; n++) p[n] = __expf(dt * A[n]);
  }
}

// ---------------- MFMA GEMM: C[M,N] = X[M,K](bf16) @ W[N,K](bf16)^T ----------
template <int BM, int BN, int ACT, typename TC>
__global__ void __launch_bounds__((BM / 64) * (BN / 64) * 64) k_mfma(
    const unsigned short* __restrict__ X, int lda,
    const unsigned short* __restrict__ W, int ldb,
    const float* __restrict__ bias, TC* __restrict__ C, long ldc, int K) {
  constexpr int NW = (BM / 64) * (BN / 64);
  constexpr int WN = BN / 64;
  constexpr int SEGS = (BM + BN) / 16;
  __shared__ unsigned short As[BM * 32];
  __shared__ unsigned short Bs[BN * 32];
  int tid = threadIdx.x;
  int wave = tid >> 6, lane = tid & 63;
  int wm = wave / WN, wn = wave % WN;
  long row0 = (long)blockIdx.y * BM;
  long col0 = (long)blockIdx.x * BN;
  int srow = lane >> 2;
  int kchunk = (lane & 3) ^ (srow & 3);
  f32x4 acc[4][4] = {};
  for (int k0 = 0; k0 < K; k0 += 32) {
#pragma unroll
    for (int s = wave; s < SEGS; s += NW) {
      if (s < BM / 16) {
        const unsigned short* g =
            X + (row0 + s * 16 + srow) * (long)lda + k0 + kchunk * 8;
        gl_lds16(g, &As[s * 16 * 32]);
      } else {
        int s2 = s - BM / 16;
        const unsigned short* g =
            W + (col0 + s2 * 16 + srow) * (long)ldb + k0 + kchunk * 8;
        gl_lds16(g, &Bs[s2 * 16 * 32]);
      }
    }
    __syncthreads();
    int fr = lane & 15;
    int slot = (lane >> 4) ^ (lane & 3);
    bf16x8 af[4], bfr[4];
#pragma unroll
    for (int i = 0; i < 4; i++)
      af[i] = *(const bf16x8*)&As[(wm * 64 + i * 16 + fr) * 32 + slot * 8];
#pragma unroll
    for (int j = 0; j < 4; j++)
      bfr[j] = *(const bf16x8*)&Bs[(wn * 64 + j * 16 + fr) * 32 + slot * 8];
#pragma unroll
    for (int i = 0; i < 4; i++)
#pragma unroll
      for (int j = 0; j < 4; j++)
        acc[i][j] = __builtin_amdgcn_mfma_f32_16x16x32_bf16(af[i], bfr[j],
                                                            acc[i][j], 0, 0, 0);
    __syncthreads();
  }
#pragma unroll
  for (int i = 0; i < 4; i++) {
#pragma unroll
    for (int j = 0; j < 4; j++) {
      long rbase = row0 + wm * 64 + i * 16 + ((lane >> 4) << 2);
      long c = col0 + wn * 64 + j * 16 + (lane & 15);
#pragma unroll
      for (int reg = 0; reg < 4; reg++) {
        float v = acc[i][j][reg];
        long r = rbase + reg;
        if constexpr (ACT == 1) {
          v += bias[c];
          v = fmaxf(v, 0.f) + log1pf(__expf(-fabsf(v)));  // softplus
        }
        st1(&C[r * ldc + c], v);
      }
    }
  }
}

// ---------------- fused x_proj + dt_proj ----------------
__global__ void __launch_bounds__(256) k_xdt(
    const unsigned short* __restrict__ Xc,   // xc bf16, lda=1024
    const unsigned short* __restrict__ Wx,   // 64x1024 bf16
    const unsigned short* __restrict__ Wdt,  // 1024x32 bf16
    const float* __restrict__ bdt,           // 1024 fp32
    float* __restrict__ bc,                  // 16384x32 fp32 (B|C packed)
    __half* __restrict__ dt) {               // stride 2048 (x-half of xz)
  __shared__ unsigned short As[64 * 32];
  __shared__ unsigned short Bs[64 * 32];
  __shared__ unsigned short Xt[64 * 40];
  int tid = threadIdx.x;
  int wave = tid >> 6, lane = tid & 63;
  int wm = wave >> 1, wn = wave & 1;
  long row0 = (long)blockIdx.x * 64;
  int srow = lane >> 2;
  int kchunk = (lane & 3) ^ (srow & 3);
  int fr = lane & 15;
  int q = lane >> 4;
  f32x4 acc[2][2] = {};
  for (int k0 = 0; k0 < DI_; k0 += 32) {
#pragma unroll
    for (int s = wave; s < 8; s += 4) {
      if (s < 4)
        gl_lds16(Xc + (row0 + s * 16 + srow) * (long)DI_ + k0 + kchunk * 8,
                 &As[s * 16 * 32]);
      else
        gl_lds16(Wx + ((s - 4) * 16 + srow) * (long)DI_ + k0 + kchunk * 8,
                 &Bs[(s - 4) * 16 * 32]);
    }
    __syncthreads();
    int slot = q ^ (lane & 3);
    bf16x8 af[2], bfr[2];
#pragma unroll
    for (int i = 0; i < 2; i++)
      af[i] = *(const bf16x8*)&As[(wm * 32 + i * 16 + fr) * 32 + slot * 8];
#pragma unroll
    for (int j = 0; j < 2; j++)
      bfr[j] = *(const bf16x8*)&Bs[(wn * 32 + j * 16 + fr) * 32 + slot * 8];
#pragma unroll
    for (int i = 0; i < 2; i++)
#pragma unroll
      for (int j = 0; j < 2; j++)
        acc[i][j] = __builtin_amdgcn_mfma_f32_16x16x32_bf16(af[i], bfr[j],
                                                            acc[i][j], 0, 0, 0);
    __syncthreads();
  }
#pragma unroll
  for (int i = 0; i < 2; i++) {
#pragma unroll
    for (int j = 0; j < 2; j++) {
      int c = wn * 32 + j * 16 + fr;
      int lr0 = wm * 32 + i * 16 + (q << 2);
#pragma unroll
      for (int reg = 0; reg < 4; reg++) {
        float v = acc[i][j][reg];
        int lr = lr0 + reg;
        if (c < 32)
          Xt[lr * 40 + c] = f2bfbits(v);        // xdt tile
        else
          bc[(row0 + lr) * 32 + (c - 32)] = v;  // packed B|C rows (stride 32)
      }
    }
  }
  __syncthreads();
  // phase 2: dt = softplus(xdt @ Wdt^T + bdt)
  bf16x8 xa[4];
#pragma unroll
  for (int i = 0; i < 4; i++)
    xa[i] = *(const bf16x8*)&Xt[(i * 16 + fr) * 40 + q * 8];
#pragma unroll
  for (int nt = 0; nt < 16; nt++) {
    int c = wave * 256 + nt * 16 + fr;
    bf16x8 wb = *(const bf16x8*)&Wdt[(long)c * 32 + q * 8];
    float bv = bdt[c];
    f32x4 dacc[4] = {};
#pragma unroll
    for (int i = 0; i < 4; i++)
      dacc[i] = __builtin_amdgcn_mfma_f32_16x16x32_bf16(xa[i], wb, dacc[i], 0, 0, 0);
#pragma unroll
    for (int i = 0; i < 4; i++) {
#pragma unroll
      for (int reg = 0; reg < 4; reg++) {
        float v = dacc[i][reg] + bv;
        v = fmaxf(v, 0.f) + log1pf(__expf(-fabsf(v)));  // softplus
        long r = row0 + i * 16 + (q << 2) + reg;
        st1(&dt[r * 2048 + c], v);
      }
    }
  }
}

// ---------------- weight fp32 -> bf16 conversion ----------------
__global__ void k_convert4(const float* __restrict__ s0, int n0,
                           const float* __restrict__ s1, int n1,
                           const float* __restrict__ s2, int n2,
                           const float* __restrict__ s3, int n3,
                           bf16* __restrict__ d0, bf16* __restrict__ d1,
                           bf16* __restrict__ d2, bf16* __restrict__ d3) {
  int i = blockIdx.x * 256 + threadIdx.x;
  int t0 = n0 >> 2, t1 = t0 + (n1 >> 2), t2 = t1 + (n2 >> 2), t3 = t2 + (n3 >> 2);
  const float* s;
  bf16* d;
  int loc;
  if (i < t0) { s = s0; d = d0; loc = i; }
  else if (i < t1) { s = s1; d = d1; loc = i - t0; }
  else if (i < t2) { s = s2; d = d2; loc = i - t1; }
  else if (i < t3) { s = s3; d = d3; loc = i - t2; }
  else return;
  float4 v = ((const float4*)s)[loc];
  bf16* o = d + (long)loc * 4;
  st1(o + 0, v.x); st1(o + 1, v.y); st1(o + 2, v.z); st1(o + 3, v.w);
}

// ---------------- K1: embedding + LN + gate ----------------
__global__ void k_embed(const int* __restrict__ ids, const float* __restrict__ gate,
                        const float* __restrict__ wemb, const float* __restrict__ pos2,
                        const float* __restrict__ pe, const float* __restrict__ g,
                        const float* __restrict__ bta, bf16* __restrict__ seq) {
  int row = blockIdx.x;
  int s = row % S_;
  int t = threadIdx.x;
  int id = ids[row];
  float v[2];
#pragma unroll
  for (int i = 0; i < 2; i++) {
    int h = t + i * 256;
    v[i] = pos2[s * H_ + h] * wemb[(long)id * H_ + h] + pe[s * H_ + h];
  }
  float lsum = v[0] + v[1];
  float lsq = v[0] * v[0] + v[1] * v[1];
  __shared__ float smA[4], smB[4];
  int lane = t & 63, w = t >> 6;
  lsum = wred_sum(lsum);
  lsq = wred_sum(lsq);
  if (!lane) { smA[w] = lsum; smB[w] = lsq; }
  __syncthreads();
  float tot = smA[0] + smA[1] + smA[2] + smA[3];
  float totq = smB[0] + smB[1] + smB[2] + smB[3];
  float mu = tot * (1.f / H_);
  float var = totq * (1.f / H_) - mu * mu;
  float inv = rsqrtf(fmaxf(var, 0.f) + 1e-12f);
  float gt = gate[row];
#pragma unroll
  for (int i = 0; i < 2; i++) {
    int h = t + i * 256;
    st1(&seq[(long)row * H_ + h], gt * (g[h] * (v[i] - mu) * inv + bta[h]));
  }
}

// ---------------- conv (depthwise causal, DC=4) + silu ----------------
__global__ void k_conv(const bf16* __restrict__ xz, const float* __restrict__ cw,
                       const float* __restrict__ cb, bf16* __restrict__ xc) {
  long idx = (long)blockIdx.x * 256 + threadIdx.x;
  int d = (int)(idx & 1023);
  long bt = idx >> 10;
  int t = (int)(bt & 2047);
  const unsigned short* xbase = (const unsigned short*)xz + (bt - t) * 2048 + d;
  float acc = cb[d];
#pragma unroll
  for (int k = 0; k < 4; k++) {
    int ts = t + k - 3;
    if (ts >= 0) acc += cw[d * 4 + k] * bf2f(xbase[(long)ts * 2048]);
  }
  float s = acc / (1.f + __expf(-acc));
  st1(&xc[idx], s);
}

// ---------------- serial scan (fallback when ws too small) ----------------
__global__ void __launch_bounds__(64) k_scan(
    bf16* __restrict__ xzb, const bf16* __restrict__ xc,
    const float* __restrict__ bcg, const float* __restrict__ Alog,
    const float* __restrict__ Dp) {
  int idx = blockIdx.x * 64 + threadIdx.x;
  int half = idx & 1;
  int p = idx >> 1;
  int d = p & 1023;
  int b = p >> 10;
  int n0 = half * 8;
  float A[8];
#pragma unroll
  for (int n = 0; n < 8; n++) A[n] = -__expf(Alog[d * 16 + n0 + n]);
  float Dd = Dp[d];
  float h[8] = {0, 0, 0, 0, 0, 0, 0, 0};
  const __half* dtb = (const __half*)xzb + (long)b * S_ * 2048 + d;
  const unsigned short* xb = (const unsigned short*)xc + (long)b * S_ * DI_ + d;
  const unsigned short* zb = (const unsigned short*)xzb + (long)b * S_ * 2048 + DI_ + d;
  const float* bcb = bcg + (long)b * S_ * 32 + n0;
  bf16* yb = xzb + (long)b * S_ * 2048 + d;
  for (int t = 0; t < S_; t++) {
    float dt_c = __half2float(dtb[(long)t * 2048]);
    float x_c = bf2f(xb[(long)t * DI_]);
    float z_c = bf2f(zb[(long)t * 2048]);
    const float* r = bcb + (long)t * 32;
    float dx = dt_c * x_c;
    float yacc = 0.f;
#pragma unroll
    for (int n = 0; n < 8; n++) {
      float hn = __expf(dt_c * A[n]) * h[n] + dx * r[n];
      h[n] = hn;
      yacc += hn * r[16 + n];
    }
    yacc += __shfl_xor(yacc, 1, 64);
    if (!half) {
      float sz = z_c / (1.f + __expf(-z_c));
      st1(&yb[(long)t * 2048], (yacc + Dd * x_c) * sz);
    }
  }
}

// ---------------- chunked scan phase A: clamp-free ----------------
template <bool FAST>
static __device__ __forceinline__ void scanA_body(
    const __half* dtb, const unsigned short* xb, const float* bcb,
    const float* A, int n0, int t0, float* h, float& sd) {
  float dtv[PF_], xv[PF_];
  f32x4 Bv0[PF_], Bv1[PF_];
#pragma unroll
  for (int i = 0; i < PF_; i++) {
    long o = t0 + i;
    dtv[i] = __half2float(dtb[o * 2048]);
    xv[i] = bf2f(xb[o * DI_]);
    Bv0[i] = *(const f32x4*)(bcb + o * 32);
    Bv1[i] = *(const f32x4*)(bcb + o * 32 + 4);
  }
  for (int t = 0; t < LC_; t += PF_) {
#pragma unroll
    for (int u = 0; u < PF_; u++) {
      float dt_c = dtv[u], x_c = xv[u];
      f32x4 b0 = Bv0[u], b1 = Bv1[u];
      long o = t0 + t + u + PF_;  // no clamp: max o = 1987 < S (chunks 0..30)
      dtv[u] = __half2float(dtb[o * 2048]);
      xv[u] = bf2f(xb[o * DI_]);
      Bv0[u] = *(const f32x4*)(bcb + o * 32);
      Bv1[u] = *(const f32x4*)(bcb + o * 32 + 4);
      sd += dt_c;
      float dx = dt_c * x_c;
      float p[8];
      decay8<FAST>(dt_c, A, n0, p);
#pragma unroll
      for (int n = 0; n < 4; n++) h[n] = p[n] * h[n] + dx * b0[n];
#pragma unroll
      for (int n = 0; n < 4; n++) h[4 + n] = p[4 + n] * h[4 + n] + dx * b1[n];
    }
  }
}

// grid (NC-1)*64 blocks x 256: chunks 0..NC-2 (last chunk h_final unused).
__global__ void __launch_bounds__(256) k_scanA(
    const bf16* __restrict__ xzb, const bf16* __restrict__ xc,
    const float* __restrict__ bcg, const float* __restrict__ Alog,
    __half* __restrict__ hf, __half* __restrict__ sdt) {
  int idx = blockIdx.x * 256 + threadIdx.x;
  int pf = idx & 16383;
  int c = idx >> 14;
  int half = pf & 1;
  int p = pf >> 1;
  int d = p & 1023;
  int b = p >> 10;
  int n0 = half * 8;
  float A[8];
  bool fast = true;
#pragma unroll
  for (int n = 0; n < 8; n++) {
    A[n] = -__expf(Alog[d * 16 + n0 + n]);
    fast = fast && (fabsf(A[n] + (float)(n0 + n + 1)) < 1e-3f);
  }
  const __half* dtb = (const __half*)xzb + (long)b * S_ * 2048 + d;
  const unsigned short* xb = (const unsigned short*)xc + (long)b * S_ * DI_ + d;
  const float* bcb = bcg + (long)b * S_ * 32 + n0;
  int t0 = c * LC_;
  float h[8] = {0, 0, 0, 0, 0, 0, 0, 0};
  float sd = 0.f;
  if (fast) scanA_body<true>(dtb, xb, bcb, A, n0, t0, h, sd);
  else scanA_body<false>(dtb, xb, bcb, A, n0, t0, h, sd);
  u16x8 pk;
#pragma unroll
  for (int n = 0; n < 8; n++) pk[n] = h2bits(h[n]);
  *(u16x8*)&hf[(long)idx * 8] = pk;
  if (!half) st1(&sdt[c * 8192 + p], sd);
}

// ---------------- phase B: in-place prefix fold of chunk summaries ----------
// After this, hf[j] holds h_start for chunk j+1 (fold of chunks 0..j).
__global__ void __launch_bounds__(256) k_scanB(
    const float* __restrict__ Alog, __half* __restrict__ hf,
    const __half* __restrict__ sdt) {
  int pf = blockIdx.x * 256 + threadIdx.x;  // 0..16383
  int half = pf & 1;
  int p = pf >> 1;
  int d = p & 1023;
  int n0 = half * 8;
  float A[8];
  bool fast = true;
#pragma unroll
  for (int n = 0; n < 8; n++) {
    A[n] = -__expf(Alog[d * 16 + n0 + n]);
    fast = fast && (fabsf(A[n] + (float)(n0 + n + 1)) < 1e-3f);
  }
  float h[8] = {0, 0, 0, 0, 0, 0, 0, 0};
  for (int j = 0; j < NC_ - 1; j++) {
    float sd = __half2float(sdt[j * 8192 + p]);
    __half* hj = hf + ((long)j * 16384 + pf) * 8;
    u16x8 hb = *(const u16x8*)hj;
    float pw[8];
    if (fast) decay8<true>(sd, A, n0, pw);
    else decay8<false>(sd, A, n0, pw);
    u16x8 pk;
#pragma unroll
    for (int n = 0; n < 8; n++) {
      h[n] = pw[n] * h[n] + bits2h(hb[n]);
      pk[n] = h2bits(h[n]);
    }
    *(u16x8*)hj = pk;
  }
}

// ---------------- phase C: rescan chunk with y output; dt-only clamp --------
template <bool FAST>
static __device__ __forceinline__ void scanC_body(
    const __half* dtb, const unsigned short* xb, const unsigned short* zb,
    const float* bcb, bf16* yb, const float* A, int n0, int half, int t0,
    float Dd, float* h) {
  int tend = t0 + LC_ - 1;  // clamp ONLY dt (y overwrites dt across chunks)
  float dtv[PF_], xv[PF_], zv[PF_];
  f32x4 Bv0[PF_], Bv1[PF_], Cv0[PF_], Cv1[PF_];
#pragma unroll
  for (int i = 0; i < PF_; i++) {
    long o = t0 + i;
    dtv[i] = __half2float(dtb[o * 2048]);
    xv[i] = bf2f(xb[o * DI_]);
    zv[i] = bf2f(zb[o * 2048]);
    Bv0[i] = *(const f32x4*)(bcb + o * 32);
    Bv1[i] = *(const f32x4*)(bcb + o * 32 + 4);
    Cv0[i] = *(const f32x4*)(bcb + o * 32 + 16);
    Cv1[i] = *(const f32x4*)(bcb + o * 32 + 20);
  }
  for (int t = 0; t < LC_; t += PF_) {
#pragma unroll
    for (int u = 0; u < PF_; u++) {
      float dt_c = dtv[u], x_c = xv[u], z_c = zv[u];
      f32x4 b0 = Bv0[u], b1 = Bv1[u], c0 = Cv0[u], c1 = Cv1[u];
      long o = t0 + t + u + PF_;
      long od = o > tend ? tend : o;  // dt only
      dtv[u] = __half2float(dtb[od * 2048]);
      xv[u] = bf2f(xb[o * DI_]);          // overread lands in ws, unused
      zv[u] = bf2f(zb[o * 2048]);
      Bv0[u] = *(const f32x4*)(bcb + o * 32);
      Bv1[u] = *(const f32x4*)(bcb + o * 32 + 4);
      Cv0[u] = *(const f32x4*)(bcb + o * 32 + 16);
      Cv1[u] = *(const f32x4*)(bcb + o * 32 + 20);
      float dx = dt_c * x_c;
      float p[8];
      decay8<FAST>(dt_c, A, n0, p);
      float yacc = 0.f;
#pragma unroll
      for (int n = 0; n < 4; n++) {
        float hn = p[n] * h[n] + dx * b0[n];
        h[n] = hn;
        yacc += hn * c0[n];
      }
#pragma unroll
      for (int n = 0; n < 4; n++) {
        float hn = p[4 + n] * h[4 + n] + dx * b1[n];
        h[4 + n] = hn;
        yacc += hn * c1[n];
      }
      yacc += __shfl_xor(yacc, 1, 64);
      if (!half) {
        float sz = z_c / (1.f + __expf(-z_c));
        st1(&yb[(long)(t0 + t + u) * 2048], (yacc + Dd * x_c) * sz);
      }
    }
  }
}

__global__ void __launch_bounds__(256) k_scanC(
    bf16* __restrict__ xzb, const bf16* __restrict__ xc,
    const float* __restrict__ bcg, const float* __restrict__ Alog,
    const float* __restrict__ Dp, const __half* __restrict__ hf) {
  int idx = blockIdx.x * 256 + threadIdx.x;
  int pf = idx & 16383;
  int c = idx >> 14;
  int half = pf & 1;
  int p = pf >> 1;
  int d = p & 1023;
  int b = p >> 10;
  int n0 = half * 8;
  float A[8];
  bool fast = true;
#pragma unroll
  for (int n = 0; n < 8; n++) {
    A[n] = -__expf(Alog[d * 16 + n0 + n]);
    fast = fast && (fabsf(A[n] + (float)(n0 + n + 1)) < 1e-3f);
  }
  float Dd = Dp[d];
  float h[8] = {0, 0, 0, 0, 0, 0, 0, 0};
  if (c > 0) {
    u16x8 hb = *(const u16x8*)&hf[((long)(c - 1) * 16384 + pf) * 8];
#pragma unroll
    for (int n = 0; n < 8; n++) h[n] = bits2h(hb[n]);
  }
  const __half* dtb = (const __half*)xzb + (long)b * S_ * 2048 + d;
  const unsigned short* xb = (const unsigned short*)xc + (long)b * S_ * DI_ + d;
  const unsigned short* zb = (const unsigned short*)xzb + (long)b * S_ * 2048 + DI_ + d;
  const float* bcb = bcg + (long)b * S_ * 32 + n0;
  bf16* yb = xzb + (long)b * S_ * 2048 + d;
  int t0 = c * LC_;
  if (fast) scanC_body<true>(dtb, xb, zb, bcb, yb, A, n0, half, t0, Dd, h);
  else scanC_body<false>(dtb, xb, zb, bcb, yb, A, n0, half, t0, Dd, h);
}

// ---------------- residual + LN + gate (in-place on seq) ----------------
__global__ void k_resid_ln(const bf16* __restrict__ hb, const float* __restrict__ gate,
                           const float* __restrict__ g, const float* __restrict__ bta,
                           bf16* __restrict__ seq) {
  int row = blockIdx.x;
  int t = threadIdx.x;
  float v[2];
#pragma unroll
  for (int i = 0; i < 2; i++) {
    int h = t + i * 256;
    v[i] = bf2f(((const unsigned short*)hb)[(long)row * H_ + h]) +
           bf2f(((const unsigned short*)seq)[(long)row * H_ + h]);
  }
  float lsum = v[0] + v[1];
  float lsq = v[0] * v[0] + v[1] * v[1];
  __shared__ float smA[4], smB[4];
  int lane = t & 63, w = t >> 6;
  lsum = wred_sum(lsum);
  lsq = wred_sum(lsq);
  if (!lane) { smA[w] = lsum; smB[w] = lsq; }
  __syncthreads();
  float tot = smA[0] + smA[1] + smA[2] + smA[3];
  float totq = smB[0] + smB[1] + smB[2] + smB[3];
  float mu = tot * (1.f / H_);
  float var = totq * (1.f / H_) - mu * mu;
  float inv = rsqrtf(fmaxf(var, 0.f) + 1e-12f);
  float gt = gate[row];
#pragma unroll
  for (int i = 0; i < 2; i++) {
    int h = t + i * 256;
    st1(&seq[(long)row * H_ + h], gt * (g[h] * (v[i] - mu) * inv + bta[h]));
  }
}

// ---------------- max pool (two stage) ----------------
__global__ void k_pool1(const bf16* __restrict__ seq, const float* __restrict__ gate,
                        float* __restrict__ part) {
  int blk = blockIdx.x;
  int b = blk >> 4, c = blk & 15;
  int h = threadIdx.x;
  float m = -3.4e38f;
  for (int i = 0; i < 128; i++) {
    long r = (long)b * S_ + c * 128 + i;
    m = fmaxf(m, bf2f(((const unsigned short*)seq)[r * H_ + h]) * gate[r]);
  }
  part[((long)b * 16 + c) * H_ + h] = m;
}
__global__ void k_pool2(const float* __restrict__ part, float* __restrict__ pooled) {
  int idx = blockIdx.x * 256 + threadIdx.x;
  int b = idx >> 9, h = idx & 511;
  float m = -3.4e38f;
#pragma unroll
  for (int c = 0; c < 16; c++) m = fmaxf(m, part[((long)b * 16 + c) * H_ + h]);
  pooled[idx] = m;
}

// ---------------- dense2 + gelu_new ----------------
__global__ void k_feat(const float* __restrict__ pooled, const float* __restrict__ W2,
                       const float* __restrict__ b2, float* __restrict__ feat) {
  int b = blockIdx.x;
  int j = threadIdx.x;
  __shared__ float ps[512];
  ps[j] = pooled[b * 512 + j];
  __syncthreads();
  float acc = b2[j];
  const float* wr = W2 + (long)j * 512;
  for (int k = 0; k < 512; k++) acc += ps[k] * wr[k];
  float x = acc;
  float u = 0.7978845608028654f * (x + 0.044715f * x * x * x);
  feat[b * 512 + j] = 0.5f * x * (1.f + tanhf(u));
}

// ---------------- GroupNorm + FiLM(style) + head ----------------
__global__ void k_head(const float* __restrict__ feat, const float* __restrict__ age_sex,
                       const float* __restrict__ mw, const float* __restrict__ mb,
                       const float* __restrict__ gng, const float* __restrict__ gnb,
                       const float* __restrict__ hw, const float* __restrict__ hb,
                       float* __restrict__ out) {
  int b = blockIdx.x;
  int j = threadIdx.x;
  float f = feat[b * 512 + j];
  __shared__ float sA[8], sB[8];
  int lane = j & 63, w = j >> 6;
  float s1 = wred_sum(f);
  float s2 = wred_sum(f * f);
  if (!lane) { sA[w] = s1; sB[w] = s2; }
  __syncthreads();
  int g = j >> 7;
  float tot = sA[2 * g] + sA[2 * g + 1];
  float totq = sB[2 * g] + sB[2 * g + 1];
  float mu = tot * (1.f / 128.f);
  float var = totq * (1.f / 128.f) - mu * mu;
  float gn = (f - mu) * rsqrtf(fmaxf(var, 0.f) + 1e-5f) * gng[j] + gnb[j];
  float a0 = age_sex[b * 2], a1 = age_sex[b * 2 + 1];
  float sa = a0 * mw[j * 2] + a1 * mw[j * 2 + 1] + mb[j];
  sa = sa > 0.f ? sa : (__expf(sa) - 1.f);
  int j2 = 512 + j;
  float sb = a0 * mw[j2 * 2] + a1 * mw[j2 * 2 + 1] + mb[j2];
  sb = sb > 0.f ? sb : (__expf(sb) - 1.f);
  float feature = (1.f + sa) * gn + sb;
  out[16 + 16384 + b * 512 + j] = feature;
  float l0 = feature * hw[j];
  float l1 = feature * hw[512 + j];
  __syncthreads();
  l0 = wred_sum(l0);
  l1 = wred_sum(l1);
  if (!lane) { sA[w] = l0; sB[w] = l1; }
  __syncthreads();
  if (j == 0) {
    float t0 = 0.f, t1 = 0.f;
#pragma unroll
    for (int i = 0; i < 8; i++) { t0 += sA[i]; t1 += sB[i]; }
    out[b * 2 + 0] = t0 + hb[0];
    out[b * 2 + 1] = t1 + hb[1];
  }
}

__global__ void k_copy(const float* __restrict__ src, float* __restrict__ dst, int n) {
  int i = blockIdx.x * 256 + threadIdx.x;
  if (i < n) dst[i] = src[i];
}

// ---------------- launch ----------------
extern "C" void kernel_launch(void* const* d_in, const int* in_sizes, int n_in,
                              void* d_out, int out_size, void* d_ws, size_t ws_size,
                              hipStream_t stream) {
  const int* ids = (const int*)d_in[0];
  const float* gate = (const float*)d_in[1];
  const float* age_sex = (const float*)d_in[2];
  const float* word_emb = (const float*)d_in[3];
  const float* pos_emb2 = (const float*)d_in[4];
  const float* pe = (const float*)d_in[5];
  const float* emb_ln_g = (const float*)d_in[6];
  const float* emb_ln_b = (const float*)d_in[7];
  const float* in_proj_w = (const float*)d_in[8];
  const float* conv_w = (const float*)d_in[9];
  const float* conv_b = (const float*)d_in[10];
  const float* x_proj_w = (const float*)d_in[11];
  const float* dt_proj_w = (const float*)d_in[12];
  const float* dt_proj_b = (const float*)d_in[13];
  const float* A_log = (const float*)d_in[14];
  const float* D_param = (const float*)d_in[15];
  const float* out_proj_w = (const float*)d_in[16];
  const float* blk_ln_g = (const float*)d_in[17];
  const float* blk_ln_b = (const float*)d_in[18];
  const float* dense2_w = (const float*)d_in[19];
  const float* dense2_b = (const float*)d_in[20];
  const float* male_fc_w = (const float*)d_in[21];
  const float* male_fc_b = (const float*)d_in[22];
  const float* gn_g = (const float*)d_in[23];
  const float* gn_b = (const float*)d_in[24];
  const float* head_w = (const float*)d_in[25];
  const float* head_b = (const float*)d_in[26];
  float* out = (float*)d_out;

  // ws layout (bytes), total 131,809,280 (< 128 MiB = 134,217,728)
  char* w = (char*)d_ws;
  bf16* seq = (bf16*)(w);                    //  16,777,216
  bf16* xz = (bf16*)(w + 16777216);          //  67,108,864
  bf16* xc = (bf16*)(w + 83886080);          //  33,554,432 (also hbuf)
  float* bc = (float*)(w + 117440512);       //   2,097,152 (16384x32 fp32)
  bf16* wi_b = (bf16*)(w + 119537664);       //   2,097,152
  bf16* wx_b = (bf16*)(w + 121634816);       //     131,072
  bf16* wdt_b = (bf16*)(w + 121765888);      //      65,536
  bf16* wo_b = (bf16*)(w + 121831424);       //   1,048,576
  float* part = (float*)(w + 122880000);     //     262,144
  float* pooled = (float*)(w + 123142144);   //      16,384
  float* featp = (float*)(w + 123158528);    //      16,384
  __half* hf = (__half*)(w + 123174912);     //   8,126,464 (31*16384*8 fp16)
  __half* sdt = (__half*)(w + 131301376);    //     507,904 (31*8192 fp16)
  const bool chunked = ws_size >= (size_t)131809280;

  k_embed<<<B_ * S_, 256, 0, stream>>>(ids, gate, word_emb, pos_emb2, pe, emb_ln_g,
                                       emb_ln_b, seq);

  const int nWi = 2 * DI_ * H_;
  const int nWx = 64 * DI_;
  const int nWdt = DI_ * DR_;
  const int nWo = H_ * DI_;
  const int cvt_blocks = (nWi + nWx + nWdt + nWo) / 4 / 256;

  for (int l = 0; l < NL_; l++) {
    const float* Wi = in_proj_w + (long)l * nWi;
    const float* cw = conv_w + (long)l * DI_ * DC_;
    const float* cb = conv_b + (long)l * DI_;
    const float* Wx = x_proj_w + (long)l * nWx;
    const float* Wdt = dt_proj_w + (long)l * nWdt;
    const float* bdt = dt_proj_b + (long)l * DI_;
    const float* Al = A_log + (long)l * DI_ * DS_;
    const float* Dl = D_param + (long)l * DI_;
    const float* Wo = out_proj_w + (long)l * nWo;
    const float* bg = blk_ln_g + (long)l * H_;
    const float* bb = blk_ln_b + (long)l * H_;

    k_convert4<<<cvt_blocks, 256, 0, stream>>>(Wi, nWi, Wx, nWx, Wdt, nWdt, Wo, nWo,
                                               wi_b, wx_b, wdt_b, wo_b);

    // xz = seq @ Wi^T
    k_mfma<128, 128, 0, bf16><<<dim3(16, 128), 256, 0, stream>>>(
        (const unsigned short*)seq, H_, (const unsigned short*)wi_b, H_, nullptr,
        xz, 2048, H_);
    // conv + silu -> xc
    k_conv<<<(B_ * S_ * DI_) / 256, 256, 0, stream>>>(xz, cw, cb, xc);
    // fused x_proj + dt_proj: bc (fp32, stride 32) + dt (fp16 into xz x-half)
    k_xdt<<<256, 256, 0, stream>>>(
        (const unsigned short*)xc, (const unsigned short*)wx_b,
        (const unsigned short*)wdt_b, bdt, bc, (__half*)xz);
    if (chunked) {
      k_scanA<<<(NC_ - 1) * 64, 256, 0, stream>>>(xz, xc, bc, Al, hf, sdt);
      k_scanB<<<64, 256, 0, stream>>>(Al, hf, sdt);
      k_scanC<<<NC_ * 64, 256, 0, stream>>>(xz, xc, bc, Al, Dl, hf);
    } else {
      k_scan<<<256, 64, 0, stream>>>(xz, xc, bc, Al, Dl);
    }
    // h = y @ Wo^T -> hbuf (= xc region)
    k_mfma<128, 128, 0, bf16><<<dim3(4, 128), 256, 0, stream>>>(
        (const unsigned short*)xz, 2048, (const unsigned short*)wo_b, DI_, nullptr,
        xc, H_, DI_);
    k_resid_ln<<<B_ * S_, 256, 0, stream>>>(xc, gate, bg, bb, seq);
  }

  k_pool1<<<B_ * 16, 512, 0, stream>>>(seq, gate, part);
  k_pool2<<<16, 256, 0, stream>>>(part, pooled);
  k_feat<<<B_, 512, 0, stream>>>(pooled, dense2_w, dense2_b, featp);
  k_head<<<B_, 512, 0, stream>>>(featp, age_sex, male_fc_w, male_fc_b, gn_g, gn_b,
                                 head_w, head_b, out);
  k_copy<<<(B_ * S_ + 255) / 256, 256, 0, stream>>>(gate, out + 16, B_ * S_);
}